// Round 7
// baseline (5705.952 us; speedup 1.0000x reference)
//
#include <hip/hip_runtime.h>
#include <hip/hip_bf16.h>

#define B_DIM 2
#define T_DIM 320
#define L_DIM 207
#define D_DIM 64
#define S_DIM 21
#define J_TOT (S_DIM * L_DIM)   // 4347
#define MPAD 224                // m padded to 7*32
#define IPAD 256                // i padded for pp chunks
#define NSPLIT 4
#define TSPLIT 80               // 320/4
#define NCH_A 32
#define CH_A 136                // ceil(4347/32)
#define NCH_P 128
#define CH_P 34                 // ceil(4347/128)
#define LD_ROW (L_DIM * D_DIM)  // 13248
#define LROW 72                 // k_sim LDS row stride (64 + 8 pad)
#define KROW 40                 // k_out LDS row stride (32 + 8 pad)

typedef __attribute__((ext_vector_type(8))) short bf16x8;   // 8 bf16 (4 VGPRs)
typedef __attribute__((ext_vector_type(4))) float f32x4;

__device__ inline unsigned short f2bf(float f) {
    unsigned int u = __builtin_bit_cast(unsigned int, f);
    u = (u + 0x7FFFu + ((u >> 16) & 1u)) >> 16;   // RNE
    return (unsigned short)u;
}

__device__ inline int shift_p(int s) { return (s == 0) ? 287 : (21 - s); }
__device__ inline int imin(int a, int b) { return a < b ? a : b; }
__device__ inline int imax(int a, int b) { return a > b ? a : b; }

// K0: x fp32 [B,T,L,D] -> xbf bf16 [B,T,L,D] and xt bf16 [B,T][mc7][d64][mi32]
__global__ void __launch_bounds__(256) k_prep(const float* __restrict__ x,
                                              unsigned short* __restrict__ xbf,
                                              unsigned short* __restrict__ xt) {
    __shared__ float tile[L_DIM * 66];
    int bt = blockIdx.x;
    const float* src = x + (size_t)bt * LD_ROW;
    int tid = threadIdx.x;
    for (int idx = tid; idx < L_DIM * D_DIM; idx += 256) {
        int l = idx >> 6, d = idx & 63;
        tile[l * 66 + d] = src[idx];
    }
    __syncthreads();
    unsigned short* dst1 = xbf + (size_t)bt * LD_ROW;
    for (int idx = tid; idx < L_DIM * D_DIM; idx += 256) {
        int l = idx >> 6, d = idx & 63;
        dst1[idx] = f2bf(tile[l * 66 + d]);
    }
    // xt_new[bt][mc][d][mi], m = mc*32+mi
    unsigned short* dst2 = xt + (size_t)bt * (7 * 64 * 32);
    if (tid < MPAD) {
        int mc = tid >> 5, mi = tid & 31;
        for (int d = 0; d < D_DIM; ++d) {
            float v = (tid < L_DIM) ? tile[tid * 66 + d] : 0.0f;
            dst2[(mc * 64 + d) * 32 + mi] = f2bf(v);
        }
    }
}

// ---------------- K1: logit partials (LDS-staged, 4 waves, 128x128 C) --------
__global__ void __launch_bounds__(256) k_sim(const unsigned short* __restrict__ xbf,
                                             float* __restrict__ part) {
    __shared__ __align__(16) unsigned short As[128 * LROW];
    __shared__ __align__(16) unsigned short Bs[128 * LROW];

    int id = blockIdx.x;
    int bsplit = id & 7;
    int b = bsplit >> 2, split = bsplit & 3;
    int rest = id >> 3;          // 0..83
    int s = rest >> 2;           // 0..20
    int tile = rest & 3;
    int l0 = (tile >> 1) * 128, m0 = (tile & 1) * 128;

    int p = shift_p(s);
    int nt = T_DIM - p;
    int t0 = split * TSPLIT;
    int t1 = imin(t0 + TSPLIT, nt);

    int tid = threadIdx.x;
    int wave = tid >> 6, lane = tid & 63;
    int wl = wave >> 1, wm = wave & 1;
    int fr = lane & 15, kg = lane >> 4;

    int sr = tid >> 1, sh = tid & 1;
    int goff = sr * 64 + sh * 32;
    int loff = sr * LROW + sh * 32;

    int afo[4], bfo[4];
#pragma unroll
    for (int rg = 0; rg < 4; ++rg) afo[rg] = (wl * 64 + rg * 16 + fr) * LROW + kg * 8;
#pragma unroll
    for (int cg = 0; cg < 4; ++cg) bfo[cg] = (wm * 64 + cg * 16 + fr) * LROW + kg * 8;

    f32x4 acc[4][4];
#pragma unroll
    for (int i = 0; i < 4; ++i)
#pragma unroll
        for (int j = 0; j < 4; ++j) acc[i][j] = f32x4{0.f, 0.f, 0.f, 0.f};

    const size_t bbase = (size_t)b * T_DIM * LD_ROW;
    const unsigned short* ga = xbf + bbase + (size_t)l0 * 64;
    const unsigned short* gb = xbf + bbase + (size_t)p * LD_ROW + (size_t)m0 * 64;

    for (int t = t0; t < t1; ++t) {
        const unsigned short* pa = ga + (size_t)t * LD_ROW + goff;
        const unsigned short* pb = gb + (size_t)t * LD_ROW + goff;
        bf16x8 va[4], vb[4];
#pragma unroll
        for (int c = 0; c < 4; ++c) {
            va[c] = *(const bf16x8*)(pa + c * 8);
            vb[c] = *(const bf16x8*)(pb + c * 8);
        }
        __syncthreads();
#pragma unroll
        for (int c = 0; c < 4; ++c) {
            *(bf16x8*)(As + loff + c * 8) = va[c];
            *(bf16x8*)(Bs + loff + c * 8) = vb[c];
        }
        __syncthreads();
#pragma unroll
        for (int kd = 0; kd < 2; ++kd) {
            bf16x8 af[4], bv[4];
#pragma unroll
            for (int rg = 0; rg < 4; ++rg) af[rg] = *(const bf16x8*)(As + afo[rg] + kd * 32);
#pragma unroll
            for (int cg = 0; cg < 4; ++cg) bv[cg] = *(const bf16x8*)(Bs + bfo[cg] + kd * 32);
#pragma unroll
            for (int rg = 0; rg < 4; ++rg)
#pragma unroll
                for (int cg = 0; cg < 4; ++cg)
                    acc[rg][cg] = __builtin_amdgcn_mfma_f32_16x16x32_bf16(af[rg], bv[cg], acc[rg][cg], 0, 0, 0);
        }
    }

    float* pdst = part + ((size_t)(split * B_DIM + b) * J_TOT + (size_t)s * L_DIM) * L_DIM;
#pragma unroll
    for (int rg = 0; rg < 4; ++rg)
#pragma unroll
        for (int cg = 0; cg < 4; ++cg) {
            int col = m0 + wm * 64 + cg * 16 + fr;
            if (col < L_DIM) {
#pragma unroll
                for (int r = 0; r < 4; ++r) {
                    int row = l0 + wl * 64 + rg * 16 + kg * 4 + r;
                    if (row < L_DIM) pdst[(size_t)row * L_DIM + col] = acc[rg][cg][r];
                }
            }
        }
}

// K2: partial sum of exp over j-chunks. grid (NCH_A, B), block 256 (thread = m).
__global__ void __launch_bounds__(256) k_sumexp(const float* __restrict__ part,
                                                const float* __restrict__ w,
                                                float* __restrict__ psum) {
    int c = blockIdx.x, b = blockIdx.y;
    int m = threadIdx.x;
    if (m >= L_DIM) return;
    float scale = w[0] / (float)T_DIM;
    int j0 = c * CH_A, j1 = imin(j0 + CH_A, J_TOT);
    float acc = 0.0f;
    for (int j = j0; j < j1; ++j) {
        float v = 0.0f;
#pragma unroll
        for (int r = 0; r < NSPLIT; ++r)
            v += part[((size_t)(r * B_DIM + b) * J_TOT + j) * L_DIM + m];
        acc += __expf(v * scale);
    }
    psum[(b * NCH_A + c) * L_DIM + m] = acc;
}

// K3: pack probs to bf16 pp[b][s][mc][i(256)][mi]. grid (NCH_P, B), block 256.
__global__ void __launch_bounds__(256) k_pack(const float* __restrict__ part,
                                              const float* __restrict__ w,
                                              const float* __restrict__ psum,
                                              unsigned short* __restrict__ pp) {
    __shared__ float sinv[L_DIM];
    int c = blockIdx.x, b = blockIdx.y;
    int tid = threadIdx.x;
    if (tid < L_DIM) {
        float g = 0.0f;
        for (int q = 0; q < NCH_A; ++q) g += psum[(b * NCH_A + q) * L_DIM + tid];
        sinv[tid] = 1.0f / g;
    }
    __syncthreads();
    if (tid >= MPAD) return;
    float scale = w[0] / (float)T_DIM;
    float inv = (tid < L_DIM) ? sinv[tid] : 0.0f;
    int mc = tid >> 5, mi = tid & 31;
    int j0 = c * CH_P, j1 = imin(j0 + CH_P, J_TOT);
    for (int j = j0; j < j1; ++j) {
        float pr = 0.0f;
        if (tid < L_DIM) {
            float v = 0.0f;
#pragma unroll
            for (int r = 0; r < NSPLIT; ++r)
                v += part[((size_t)(r * B_DIM + b) * J_TOT + j) * L_DIM + tid];
            pr = __expf(v * scale) * inv;
        }
        int i = j / S_DIM, s = j % S_DIM;
        pp[((((size_t)b * S_DIM + s) * 7 + mc) * IPAD + i) * 32 + mi] = f2bf(pr);
    }
}

// ---------------- K4: out = P @ x_shift (LDS-staged, 4 waves, i128 x t2) -----
// Grid flat 640; low 3 bits = (b, t-region) XCD swizzle. rest: tg(40) x ihalf(2).
// K-chunk cc = s*7+mc (0..146); per double-stage: stage A 2x(128x32) + B 2x2x(64x32).
__global__ void __launch_bounds__(256) k_out(const unsigned short* __restrict__ ppn,
                                             const unsigned short* __restrict__ xtn,
                                             float* __restrict__ out) {
    __shared__ __align__(16) unsigned short As[2][128 * KROW];
    __shared__ __align__(16) unsigned short Bs[2][2][64 * KROW];

    int id = blockIdx.x;
    int low = id & 7;
    int b = low >> 2, tr = low & 3;
    int rest = id >> 3;          // 0..79
    int tg = rest >> 1;          // 0..39
    int ih = rest & 1;
    int t0 = tr * TSPLIT + tg * 2;
    int i0 = ih * 128;

    int tid = threadIdx.x;
    int wave = tid >> 6, lane = tid & 63;
    int wt = wave >> 1, wi = wave & 1;
    int fr = lane & 15, kg = lane >> 4;
    int t = t0 + wt;

    // staging maps
    int ar = tid >> 1, ah = tid & 1;            // A: row 0..127, 32B half
    int agoff = ar * 32 + ah * 16;
    int aloff = ar * KROW + ah * 16;
    int br = tid >> 2, bq = tid & 3;            // B: row 0..63, 16B quarter
    int bgoff = br * 32 + bq * 8;
    int bloff = br * KROW + bq * 8;

    const unsigned short* ppb = ppn + (size_t)b * (S_DIM * 7 * IPAD * 32);
    const unsigned short* xtb = xtn + (size_t)b * (T_DIM * 7 * 64 * 32);

    int afo[4], bfo[4];
#pragma unroll
    for (int rg = 0; rg < 4; ++rg) afo[rg] = (wi * 64 + rg * 16 + fr) * KROW + kg * 8;
#pragma unroll
    for (int cg = 0; cg < 4; ++cg) bfo[cg] = (cg * 16 + fr) * KROW + kg * 8;

    f32x4 acc[4][4];
#pragma unroll
    for (int i = 0; i < 4; ++i)
#pragma unroll
        for (int j = 0; j < 4; ++j) acc[i][j] = f32x4{0.f, 0.f, 0.f, 0.f};

    int kk0 = (t0 <= 32) ? 0 : 7;   // skip s=0 chunks when invalid for both t

    for (int kk = kk0; kk < 147; kk += 2) {
        int nch = imin(2, 147 - kk);
        bf16x8 va[2][2], vb[2][2];
        for (int c = 0; c < nch; ++c) {
            int cc = kk + c;
            int s = cc / 7, mc = cc % 7;
            const unsigned short* ga = ppb + ((size_t)(s * 7 + mc) * IPAD + i0) * 32;
            va[c][0] = *(const bf16x8*)(ga + agoff);
            va[c][1] = *(const bf16x8*)(ga + agoff + 8);
            int p = shift_p(s);
#pragma unroll
            for (int u = 0; u < 2; ++u) {
                int tau = imin(t0 + u + p, T_DIM - 1);
                const unsigned short* gbp = xtb + ((size_t)tau * 7 + mc) * (64 * 32);
                vb[c][u] = *(const bf16x8*)(gbp + bgoff);
            }
        }
        __syncthreads();   // prior frag reads done
        for (int c = 0; c < nch; ++c) {
            *(bf16x8*)(As[c] + aloff) = va[c][0];
            *(bf16x8*)(As[c] + aloff + 8) = va[c][1];
#pragma unroll
            for (int u = 0; u < 2; ++u) *(bf16x8*)(Bs[c][u] + bloff) = vb[c][u];
        }
        __syncthreads();   // slabs visible
        for (int c = 0; c < nch; ++c) {
            int cc = kk + c;
            int s = cc / 7;
            // Reference zero-pads the shifted copy: contribution exists only
            // when t + p_s < T. (Round-6 bug: off-by-one admitted one bad s.)
            bool valid = (t + shift_p(s) < T_DIM);
            if (valid) {
                bf16x8 af[4], bv[4];
#pragma unroll
                for (int rg = 0; rg < 4; ++rg) af[rg] = *(const bf16x8*)(As[c] + afo[rg]);
#pragma unroll
                for (int cg = 0; cg < 4; ++cg) bv[cg] = *(const bf16x8*)(Bs[c][wt] + bfo[cg]);
#pragma unroll
                for (int rg = 0; rg < 4; ++rg)
#pragma unroll
                    for (int cg = 0; cg < 4; ++cg)
                        acc[rg][cg] = __builtin_amdgcn_mfma_f32_16x16x32_bf16(af[rg], bv[cg], acc[rg][cg], 0, 0, 0);
            }
        }
    }

    float* obase = out + (size_t)(b * T_DIM + t) * LD_ROW;
#pragma unroll
    for (int rg = 0; rg < 4; ++rg)
#pragma unroll
        for (int cg = 0; cg < 4; ++cg) {
            int d = cg * 16 + fr;
#pragma unroll
            for (int r = 0; r < 4; ++r) {
                int i = i0 + wi * 64 + rg * 16 + kg * 4 + r;
                if (i < L_DIM) obase[(size_t)i * D_DIM + d] = acc[rg][cg][r];
            }
        }
}

extern "C" void kernel_launch(void* const* d_in, const int* in_sizes, int n_in,
                              void* d_out, int out_size, void* d_ws, size_t ws_size,
                              hipStream_t stream) {
    const float* x = (const float*)d_in[0];
    const float* w = (const float*)d_in[1];
    float* out = (float*)d_out;

    char* ws = (char*)d_ws;
    size_t off = 0;
    auto carve = [&](size_t bytes) {
        void* p = ws + off;
        off += (bytes + 255) & ~(size_t)255;
        return p;
    };
    unsigned short* xbf = (unsigned short*)carve((size_t)B_DIM * T_DIM * LD_ROW * 2);          // 17.0 MB
    unsigned short* xt  = (unsigned short*)carve((size_t)B_DIM * T_DIM * 7 * 64 * 32 * 2);     // 18.4 MB
    float* part         = (float*)carve((size_t)NSPLIT * B_DIM * J_TOT * L_DIM * 4);           // 28.8 MB
    float* psum         = (float*)carve((size_t)B_DIM * NCH_A * L_DIM * 4);                    // 53 KB
    size_t pp_bytes = (size_t)B_DIM * S_DIM * 7 * IPAD * 32 * 2;                               // 4.8 MB
    unsigned short* pp  = (unsigned short*)carve(pp_bytes);

    k_prep<<<B_DIM * T_DIM, 256, 0, stream>>>(x, xbf, xt);
    k_sim<<<8 * 84, 256, 0, stream>>>(xbf, part);
    k_sumexp<<<dim3(NCH_A, B_DIM), 256, 0, stream>>>(part, w, psum);
    hipMemsetAsync(pp, 0, pp_bytes, stream);   // zero pad rows (i >= 207)
    k_pack<<<dim3(NCH_P, B_DIM), 256, 0, stream>>>(part, w, psum, pp);
    k_out<<<640, 256, 0, stream>>>(pp, xt, out);
}

// Round 8
// 455.246 us; speedup vs baseline: 12.5338x; 12.5338x over previous
//
#include <hip/hip_runtime.h>
#include <hip/hip_bf16.h>

#define B_DIM 2
#define T_DIM 320
#define L_DIM 207
#define D_DIM 64
#define S_DIM 21
#define J_TOT (S_DIM * L_DIM)   // 4347
#define MPAD 224                // m padded to 7*32
#define IPAD 256                // i padded for pp chunks
#define NSPLIT 4
#define TSPLIT 80               // 320/4
#define NCH_A 32
#define CH_A 136                // ceil(4347/32)
#define NCH_P 128
#define CH_P 34                 // ceil(4347/128)
#define LD_ROW (L_DIM * D_DIM)  // 13248
#define LROW 72                 // k_sim LDS row stride (64 + 8 pad)
#define KROW 40                 // k_out LDS row stride (32 + 8 pad)

typedef __attribute__((ext_vector_type(8))) short bf16x8;   // 8 bf16 (4 VGPRs)
typedef __attribute__((ext_vector_type(4))) float f32x4;

__device__ inline unsigned short f2bf(float f) {
    unsigned int u = __builtin_bit_cast(unsigned int, f);
    u = (u + 0x7FFFu + ((u >> 16) & 1u)) >> 16;   // RNE
    return (unsigned short)u;
}

__device__ inline int shift_p(int s) { return (s == 0) ? 287 : (21 - s); }
__device__ inline int imin(int a, int b) { return a < b ? a : b; }
__device__ inline int imax(int a, int b) { return a > b ? a : b; }

// K0: x fp32 [B,T,L,D] -> xbf bf16 [B,T,L,D] and xt bf16 [B,T][mc7][d64][mi32]
__global__ void __launch_bounds__(256) k_prep(const float* __restrict__ x,
                                              unsigned short* __restrict__ xbf,
                                              unsigned short* __restrict__ xt) {
    __shared__ float tile[L_DIM * 66];
    int bt = blockIdx.x;
    const float* src = x + (size_t)bt * LD_ROW;
    int tid = threadIdx.x;
    for (int idx = tid; idx < L_DIM * D_DIM; idx += 256) {
        int l = idx >> 6, d = idx & 63;
        tile[l * 66 + d] = src[idx];
    }
    __syncthreads();
    unsigned short* dst1 = xbf + (size_t)bt * LD_ROW;
    for (int idx = tid; idx < L_DIM * D_DIM; idx += 256) {
        int l = idx >> 6, d = idx & 63;
        dst1[idx] = f2bf(tile[l * 66 + d]);
    }
    // xt_new[bt][mc][d][mi], m = mc*32+mi
    unsigned short* dst2 = xt + (size_t)bt * (7 * 64 * 32);
    if (tid < MPAD) {
        int mc = tid >> 5, mi = tid & 31;
        for (int d = 0; d < D_DIM; ++d) {
            float v = (tid < L_DIM) ? tile[tid * 66 + d] : 0.0f;
            dst2[(mc * 64 + d) * 32 + mi] = f2bf(v);
        }
    }
}

// ---------------- K1: logit partials (LDS-staged, 4 waves, 128x128 C) --------
__global__ void __launch_bounds__(256) k_sim(const unsigned short* __restrict__ xbf,
                                             float* __restrict__ part) {
    __shared__ __align__(16) unsigned short As[128 * LROW];
    __shared__ __align__(16) unsigned short Bs[128 * LROW];

    int id = blockIdx.x;
    int bsplit = id & 7;
    int b = bsplit >> 2, split = bsplit & 3;
    int rest = id >> 3;          // 0..83
    int s = rest >> 2;           // 0..20
    int tile = rest & 3;
    int l0 = (tile >> 1) * 128, m0 = (tile & 1) * 128;

    int p = shift_p(s);
    int nt = T_DIM - p;
    int t0 = split * TSPLIT;
    int t1 = imin(t0 + TSPLIT, nt);

    int tid = threadIdx.x;
    int wave = tid >> 6, lane = tid & 63;
    int wl = wave >> 1, wm = wave & 1;
    int fr = lane & 15, kg = lane >> 4;

    int sr = tid >> 1, sh = tid & 1;
    int goff = sr * 64 + sh * 32;
    int loff = sr * LROW + sh * 32;

    int afo[4], bfo[4];
#pragma unroll
    for (int rg = 0; rg < 4; ++rg) afo[rg] = (wl * 64 + rg * 16 + fr) * LROW + kg * 8;
#pragma unroll
    for (int cg = 0; cg < 4; ++cg) bfo[cg] = (wm * 64 + cg * 16 + fr) * LROW + kg * 8;

    f32x4 acc[4][4];
#pragma unroll
    for (int i = 0; i < 4; ++i)
#pragma unroll
        for (int j = 0; j < 4; ++j) acc[i][j] = f32x4{0.f, 0.f, 0.f, 0.f};

    const size_t bbase = (size_t)b * T_DIM * LD_ROW;
    const unsigned short* ga = xbf + bbase + (size_t)l0 * 64;
    const unsigned short* gb = xbf + bbase + (size_t)p * LD_ROW + (size_t)m0 * 64;

    for (int t = t0; t < t1; ++t) {
        const unsigned short* pa = ga + (size_t)t * LD_ROW + goff;
        const unsigned short* pb = gb + (size_t)t * LD_ROW + goff;
        bf16x8 va[4], vb[4];
#pragma unroll
        for (int c = 0; c < 4; ++c) {
            va[c] = *(const bf16x8*)(pa + c * 8);
            vb[c] = *(const bf16x8*)(pb + c * 8);
        }
        __syncthreads();
#pragma unroll
        for (int c = 0; c < 4; ++c) {
            *(bf16x8*)(As + loff + c * 8) = va[c];
            *(bf16x8*)(Bs + loff + c * 8) = vb[c];
        }
        __syncthreads();
#pragma unroll
        for (int kd = 0; kd < 2; ++kd) {
            bf16x8 af[4], bv[4];
#pragma unroll
            for (int rg = 0; rg < 4; ++rg) af[rg] = *(const bf16x8*)(As + afo[rg] + kd * 32);
#pragma unroll
            for (int cg = 0; cg < 4; ++cg) bv[cg] = *(const bf16x8*)(Bs + bfo[cg] + kd * 32);
#pragma unroll
            for (int rg = 0; rg < 4; ++rg)
#pragma unroll
                for (int cg = 0; cg < 4; ++cg)
                    acc[rg][cg] = __builtin_amdgcn_mfma_f32_16x16x32_bf16(af[rg], bv[cg], acc[rg][cg], 0, 0, 0);
        }
    }

    float* pdst = part + ((size_t)(split * B_DIM + b) * J_TOT + (size_t)s * L_DIM) * L_DIM;
#pragma unroll
    for (int rg = 0; rg < 4; ++rg)
#pragma unroll
        for (int cg = 0; cg < 4; ++cg) {
            int col = m0 + wm * 64 + cg * 16 + fr;
            if (col < L_DIM) {
#pragma unroll
                for (int r = 0; r < 4; ++r) {
                    int row = l0 + wl * 64 + rg * 16 + kg * 4 + r;
                    if (row < L_DIM) pdst[(size_t)row * L_DIM + col] = acc[rg][cg][r];
                }
            }
        }
}

// K2: partial sum of exp over j-chunks. grid (NCH_A, B), block 256 (thread = m).
__global__ void __launch_bounds__(256) k_sumexp(const float* __restrict__ part,
                                                const float* __restrict__ w,
                                                float* __restrict__ psum) {
    int c = blockIdx.x, b = blockIdx.y;
    int m = threadIdx.x;
    if (m >= L_DIM) return;
    float scale = w[0] / (float)T_DIM;
    int j0 = c * CH_A, j1 = imin(j0 + CH_A, J_TOT);
    float acc = 0.0f;
    for (int j = j0; j < j1; ++j) {
        float v = 0.0f;
#pragma unroll
        for (int r = 0; r < NSPLIT; ++r)
            v += part[((size_t)(r * B_DIM + b) * J_TOT + j) * L_DIM + m];
        acc += __expf(v * scale);
    }
    psum[(b * NCH_A + c) * L_DIM + m] = acc;
}

// K3: pack probs to bf16 pp[b][s][mc][i(256)][mi]. grid (NCH_P, B), block 256.
__global__ void __launch_bounds__(256) k_pack(const float* __restrict__ part,
                                              const float* __restrict__ w,
                                              const float* __restrict__ psum,
                                              unsigned short* __restrict__ pp) {
    __shared__ float sinv[L_DIM];
    int c = blockIdx.x, b = blockIdx.y;
    int tid = threadIdx.x;
    if (tid < L_DIM) {
        float g = 0.0f;
        for (int q = 0; q < NCH_A; ++q) g += psum[(b * NCH_A + q) * L_DIM + tid];
        sinv[tid] = 1.0f / g;
    }
    __syncthreads();
    if (tid >= MPAD) return;
    float scale = w[0] / (float)T_DIM;
    float inv = (tid < L_DIM) ? sinv[tid] : 0.0f;
    int mc = tid >> 5, mi = tid & 31;
    int j0 = c * CH_P, j1 = imin(j0 + CH_P, J_TOT);
    for (int j = j0; j < j1; ++j) {
        float pr = 0.0f;
        if (tid < L_DIM) {
            float v = 0.0f;
#pragma unroll
            for (int r = 0; r < NSPLIT; ++r)
                v += part[((size_t)(r * B_DIM + b) * J_TOT + j) * L_DIM + tid];
            pr = __expf(v * scale) * inv;
        }
        int i = j / S_DIM, s = j % S_DIM;
        pp[((((size_t)b * S_DIM + s) * 7 + mc) * IPAD + i) * 32 + mi] = f2bf(pr);
    }
}

// ---------------- K4: out = P @ x_shift (LDS-staged, 4 waves, i128 x t2) -----
// Grid flat 640; low 3 bits = (b, t-region) XCD swizzle. rest: tg(40) x ihalf(2).
// Runtime s-loop over block-valid shifts, static #pragma unroll mc 0..6.
// Prefetch regs are NAMED scalars (round-7 lesson: runtime-indexed private
// arrays get demoted to scratch -> 20x slowdown). Single LDS buffer,
// 2 barriers/chunk, k_sim-style.
__global__ void __launch_bounds__(256) k_out(const unsigned short* __restrict__ ppn,
                                             const unsigned short* __restrict__ xtn,
                                             float* __restrict__ out) {
    __shared__ __align__(16) unsigned short As[128 * KROW];     // 10 KB: 128 i x 32 m
    __shared__ __align__(16) unsigned short Bs[2][64 * KROW];   // 10 KB: 2 t x 64 d x 32 m

    int id = blockIdx.x;
    int low = id & 7;
    int b = low >> 2, tr = low & 3;
    int rest = id >> 3;          // 0..79
    int tg = rest >> 1;          // 0..39
    int ih = rest & 1;
    int t0 = tr * TSPLIT + tg * 2;
    int i0 = ih * 128;

    int tid = threadIdx.x;
    int wave = tid >> 6, lane = tid & 63;
    int wt = wave >> 1, wi = wave & 1;
    int fr = lane & 15, kg = lane >> 4;
    int t = t0 + wt;

    // staging maps
    int ar = tid >> 1, ah = tid & 1;            // A: row 0..127, 32B half
    int agoff = ar * 32 + ah * 16;
    int aloff = ar * KROW + ah * 16;
    int br = tid >> 2, bq = tid & 3;            // B: row 0..63, 16B quarter
    int bgoff = br * 32 + bq * 8;
    int bloff = br * KROW + bq * 8;

    const unsigned short* ppb = ppn + (size_t)b * (S_DIM * 7 * IPAD * 32);
    const unsigned short* xtb = xtn + (size_t)b * (T_DIM * 7 * 64 * 32);

    int afo[4], bfo[4];
#pragma unroll
    for (int rg = 0; rg < 4; ++rg) afo[rg] = (wi * 64 + rg * 16 + fr) * KROW + kg * 8;
#pragma unroll
    for (int cg = 0; cg < 4; ++cg) bfo[cg] = (cg * 16 + fr) * KROW + kg * 8;

    f32x4 acc[4][4];
#pragma unroll
    for (int i = 0; i < 4; ++i)
#pragma unroll
        for (int j = 0; j < 4; ++j) acc[i][j] = f32x4{0.f, 0.f, 0.f, 0.f};

    // valid s for this block (any wave): t0 + p_s < T.  s=0 head + [sBegin..20].
    int has0 = (t0 <= 32) ? 1 : 0;
    int sBegin = imax(1, t0 - 298);
    int ns = (21 - sBegin) + has0;

    // named prefetch registers — never array-indexed
    bf16x8 rA0, rA1, rB0, rB1;

    auto loadch = [&](int s, int mc) {
        const unsigned short* ga = ppb + ((size_t)(s * 7 + mc) * IPAD + i0) * 32;
        rA0 = *(const bf16x8*)(ga + agoff);
        rA1 = *(const bf16x8*)(ga + agoff + 8);
        int p = shift_p(s);
        int tau0 = imin(t0 + p, T_DIM - 1);
        int tau1 = imin(t0 + 1 + p, T_DIM - 1);
        rB0 = *(const bf16x8*)(xtb + ((size_t)tau0 * 7 + mc) * (64 * 32) + bgoff);
        rB1 = *(const bf16x8*)(xtb + ((size_t)tau1 * 7 + mc) * (64 * 32) + bgoff);
    };
    auto sOf = [&](int k) { return (has0 && k == 0) ? 0 : sBegin + (k - has0); };

    loadch(sOf(0), 0);
    for (int k = 0; k < ns; ++k) {
        int s = sOf(k);
        int p = shift_p(s);
        bool valid = (t + p < T_DIM);   // per-wave (wave-uniform branch)
#pragma unroll
        for (int mc = 0; mc < 7; ++mc) {
            __syncthreads();            // prior chunk's frag reads done
            *(bf16x8*)(As + aloff) = rA0;
            *(bf16x8*)(As + aloff + 8) = rA1;
            *(bf16x8*)(Bs[0] + bloff) = rB0;
            *(bf16x8*)(Bs[1] + bloff) = rB1;
            __syncthreads();            // slab visible
            if (mc < 6) loadch(s, mc + 1);
            else if (k + 1 < ns) loadch(sOf(k + 1), 0);
            if (valid) {
                bf16x8 af[4], bv[4];
#pragma unroll
                for (int rg = 0; rg < 4; ++rg) af[rg] = *(const bf16x8*)(As + afo[rg]);
#pragma unroll
                for (int cg = 0; cg < 4; ++cg) bv[cg] = *(const bf16x8*)(Bs[wt] + bfo[cg]);
#pragma unroll
                for (int rg = 0; rg < 4; ++rg)
#pragma unroll
                    for (int cg = 0; cg < 4; ++cg)
                        acc[rg][cg] = __builtin_amdgcn_mfma_f32_16x16x32_bf16(af[rg], bv[cg], acc[rg][cg], 0, 0, 0);
            }
        }
    }

    float* obase = out + (size_t)(b * T_DIM + t) * LD_ROW;
#pragma unroll
    for (int rg = 0; rg < 4; ++rg)
#pragma unroll
        for (int cg = 0; cg < 4; ++cg) {
            int d = cg * 16 + fr;
#pragma unroll
            for (int r = 0; r < 4; ++r) {
                int i = i0 + wi * 64 + rg * 16 + kg * 4 + r;
                if (i < L_DIM) obase[(size_t)i * D_DIM + d] = acc[rg][cg][r];
            }
        }
}

extern "C" void kernel_launch(void* const* d_in, const int* in_sizes, int n_in,
                              void* d_out, int out_size, void* d_ws, size_t ws_size,
                              hipStream_t stream) {
    const float* x = (const float*)d_in[0];
    const float* w = (const float*)d_in[1];
    float* out = (float*)d_out;

    char* ws = (char*)d_ws;
    size_t off = 0;
    auto carve = [&](size_t bytes) {
        void* p = ws + off;
        off += (bytes + 255) & ~(size_t)255;
        return p;
    };
    unsigned short* xbf = (unsigned short*)carve((size_t)B_DIM * T_DIM * LD_ROW * 2);          // 17.0 MB
    unsigned short* xt  = (unsigned short*)carve((size_t)B_DIM * T_DIM * 7 * 64 * 32 * 2);     // 18.4 MB
    float* part         = (float*)carve((size_t)NSPLIT * B_DIM * J_TOT * L_DIM * 4);           // 28.8 MB
    float* psum         = (float*)carve((size_t)B_DIM * NCH_A * L_DIM * 4);                    // 53 KB
    size_t pp_bytes = (size_t)B_DIM * S_DIM * 7 * IPAD * 32 * 2;                               // 4.8 MB
    unsigned short* pp  = (unsigned short*)carve(pp_bytes);

    k_prep<<<B_DIM * T_DIM, 256, 0, stream>>>(x, xbf, xt);
    k_sim<<<8 * 84, 256, 0, stream>>>(xbf, part);
    k_sumexp<<<dim3(NCH_A, B_DIM), 256, 0, stream>>>(part, w, psum);
    hipMemsetAsync(pp, 0, pp_bytes, stream);   // zero pad rows (i >= 207)
    k_pack<<<dim3(NCH_P, B_DIM), 256, 0, stream>>>(part, w, psum, pp);
    k_out<<<640, 256, 0, stream>>>(pp, xt, out);
}